// Round 16
// baseline (250.175 us; speedup 1.0000x reference)
//
#include <hip/hip_runtime.h>
#include <math.h>

#define TT 512
#define GG 3
#define HH 32
#define DD 128

typedef _Float16 half8 __attribute__((ext_vector_type(8)));
typedef float f32x4 __attribute__((ext_vector_type(4)));

__device__ __forceinline__ uint32_t pack2(float a, float b) {
  auto p = __builtin_amdgcn_cvt_pkrtz(a, b);
  return __builtin_bit_cast(uint32_t, p);
}
__device__ __forceinline__ float fast_tanh(float x) {
  float e = __expf(2.0f * x);
  return 1.0f - 2.0f * __builtin_amdgcn_rcpf(1.0f + e);
}

// r15 structure (best known): 16 seqs/block, 4 waves, wave (T,P) owns j-pair;
// A rows permuted so the pair lands in C regs 0,1 (no extraction); biases in
// the MFMA C-operand; x double-buffered in registers.
__global__ __launch_bounds__(256) void gru_scan_mfma4(
    const float* __restrict__ x, const float* __restrict__ W_ih,
    const float* __restrict__ W_hh, const float* __restrict__ b_ih,
    const float* __restrict__ b_hh, float* __restrict__ hout, int B) {
  const int tid = threadIdx.x;
  const int wv = tid >> 6;
  const int lane = tid & 63;
  const int col = lane & 15;   // seq for B/C; m-row for A
  const int grp = lane >> 4;   // k-block for A/B; row-group for C
  const int T = wv >> 1;       // j-tile
  const int P = wv & 1;        // j-pair within row-group
  const int nb = B / 16;
  const int g = blockIdx.x / nb;
  const int b0 = (blockIdx.x % nb) * 16;
  const float L2E = 1.44269504088896340736f;

  __shared__ float xlds[16][TT + 1];
  __shared__ uint32_t hbuf[2][16][20];

  // ---- x preload (one-time) ----
#pragma unroll 4
  for (int i = tid; i < 16 * TT; i += 256) {
    int s = i >> 9, t = i & (TT - 1);
    xlds[s][t] = x[((size_t)(b0 + s) * TT + t) * GG + g];
  }

  // ---- A fragments, rows permuted so C regs 0,1 = this wave's j-pair ----
  half8 Af[3];
  const float* Wg = W_hh + (size_t)g * 3 * HH * HH;
  const int wrow = T * 16 + (col & ~3) + 2 * P + (col & 1);
#pragma unroll
  for (int gam = 0; gam < 3; ++gam) {
    const float sc = (gam == 2) ? 2.0f * L2E : -L2E;
    const float* src = Wg + (size_t)(gam * 32 + wrow) * HH + grp * 8;
    half8 a;
#pragma unroll
    for (int i = 0; i < 8; ++i) a[i] = (_Float16)(src[i] * sc);
    Af[gam] = a;
  }

  // ---- bias C-operands + per-wave gate constants (j = T*16+grp*4+2P+k) ----
  f32x4 CinR, CinZ, CinN;
  float wiR[2], wiZ[2], wiN[2], bN[2];
#pragma unroll
  for (int k = 0; k < 2; ++k) {
    int j = T * 16 + grp * 4 + 2 * P + k;
    wiR[k] = W_ih[g * 96 + j] * (-L2E);
    wiZ[k] = W_ih[g * 96 + 32 + j] * (-L2E);
    wiN[k] = W_ih[g * 96 + 64 + j] * (2.0f * L2E);
    bN[k] = b_ih[g * 96 + 64 + j] * (2.0f * L2E);
    float br = (b_ih[g * 96 + j] + b_hh[g * 96 + j]) * (-L2E);
    float bz = (b_ih[g * 96 + 32 + j] + b_hh[g * 96 + 32 + j]) * (-L2E);
    float bn = b_hh[g * 96 + 64 + j] * (2.0f * L2E);
    CinR[k] = br; CinR[k + 2] = br;
    CinZ[k] = bz; CinZ[k + 2] = bz;
    CinN[k] = bn; CinN[k + 2] = bn;
  }

  float ho[2] = {0.0f, 0.0f};
  for (int i = tid; i < 320; i += 256) ((uint32_t*)hbuf)[i] = 0u;  // buf 0
  __syncthreads();

  float xc = xlds[col][0];

#define GRU_STEP(SRC, DST, TNEXT)                                              \
  {                                                                            \
    half8 Bf = *(const half8*)&hbuf[SRC][col][grp * 4];                        \
    float xn = xlds[col][TNEXT];                                               \
    f32x4 Cr = __builtin_amdgcn_mfma_f32_16x16x32_f16(Af[0], Bf, CinR, 0, 0, 0); \
    f32x4 Cz = __builtin_amdgcn_mfma_f32_16x16x32_f16(Af[1], Bf, CinZ, 0, 0, 0); \
    f32x4 Cn = __builtin_amdgcn_mfma_f32_16x16x32_f16(Af[2], Bf, CinN, 0, 0, 0); \
    float pr0 = fmaf(xc, wiR[0], Cr[0]);                                       \
    float pr1 = fmaf(xc, wiR[1], Cr[1]);                                       \
    float rr0 = __builtin_amdgcn_rcpf(1.0f + __builtin_amdgcn_exp2f(pr0));     \
    float rr1 = __builtin_amdgcn_rcpf(1.0f + __builtin_amdgcn_exp2f(pr1));     \
    float pz0 = fmaf(xc, wiZ[0], Cz[0]);                                       \
    float pz1 = fmaf(xc, wiZ[1], Cz[1]);                                       \
    float zz0 = __builtin_amdgcn_rcpf(1.0f + __builtin_amdgcn_exp2f(pz0));     \
    float zz1 = __builtin_amdgcn_rcpf(1.0f + __builtin_amdgcn_exp2f(pz1));     \
    float pn0 = fmaf(rr0, Cn[0], fmaf(xc, wiN[0], bN[0]));                     \
    float pn1 = fmaf(rr1, Cn[1], fmaf(xc, wiN[1], bN[1]));                     \
    float u0 = __builtin_amdgcn_rcpf(1.0f + __builtin_amdgcn_exp2f(pn0));      \
    float u1 = __builtin_amdgcn_rcpf(1.0f + __builtin_amdgcn_exp2f(pn1));      \
    float nn0 = fmaf(-2.0f, u0, 1.0f);                                         \
    float nn1 = fmaf(-2.0f, u1, 1.0f);                                         \
    ho[0] = fmaf(zz0, ho[0] - nn0, nn0);                                       \
    ho[1] = fmaf(zz1, ho[1] - nn1, nn1);                                       \
    hbuf[DST][col][T * 8 + grp * 2 + P] = pack2(ho[0], ho[1]);                 \
    __syncthreads();                                                           \
    xc = xn;                                                                   \
  }

#pragma unroll 1
  for (int t = 0; t < TT; t += 2) {
    GRU_STEP(0, 1, t + 1)
    GRU_STEP(1, 0, (t + 2 < TT) ? (t + 2) : (TT - 1))
  }
#undef GRU_STEP

  {
    int j = T * 16 + grp * 4 + 2 * P;
    size_t base = ((size_t)(b0 + col) * GG + g) * HH + j;
    hout[base] = ho[0];
    hout[base + 1] = ho[1];
  }
}

// TWO blocks per b (4096 blocks): both compute the 128-wide out row (cheap),
// each writes half the T-range -> 2x store-stream parallelism (fill kernels
// reach 6.8 TB/s; the single-block version measured ~6.1).
__global__ __launch_bounds__(256) void epilogue(
    const float* __restrict__ ctx, const float* __restrict__ hf,
    const float* __restrict__ Wq, const float* __restrict__ bq,
    const float* __restrict__ Ws, const float* __restrict__ bs,
    const float* __restrict__ Wo, const float* __restrict__ bo,
    const float* __restrict__ logT, float* __restrict__ out, int B) {
  const int b = blockIdx.x >> 1;
  const int halfsel = blockIdx.x & 1;
  const int tid = threadIdx.x;
  __shared__ float sc[DD];
  __shared__ float sw[HH];
  __shared__ float srow[DD];
  if (tid < DD) sc[tid] = ctx[(size_t)b * DD + tid];
  __syncthreads();
  if (tid < HH) {
    float q = bq[tid];
#pragma unroll 4
    for (int d = 0; d < DD; ++d) q = fmaf(sc[d], Wq[d * HH + tid], q);
    float h0 = hf[((size_t)b * 3 + 0) * HH + tid];
    float h1 = hf[((size_t)b * 3 + 1) * HH + tid];
    float h2 = hf[((size_t)b * 3 + 2) * HH + tid];
    float wsv = Ws[tid];
    float s0 = fast_tanh(h0 + q) * wsv;
    float s1 = fast_tanh(h1 + q) * wsv;
    float s2 = fast_tanh(h2 + q) * wsv;
#pragma unroll
    for (int off = 16; off >= 1; off >>= 1) {
      s0 += __shfl_xor(s0, off, 32);
      s1 += __shfl_xor(s1, off, 32);
      s2 += __shfl_xor(s2, off, 32);
    }
    float bsv = bs[0];
    float tmp = fmaxf(__expf(logT[0]), 0.1f);
    float inv = 1.0f / tmp;
    s0 = (s0 + bsv) * inv; s1 = (s1 + bsv) * inv; s2 = (s2 + bsv) * inv;
    float m = fmaxf(s0, fmaxf(s1, s2));
    float e0 = __expf(s0 - m), e1 = __expf(s1 - m), e2 = __expf(s2 - m);
    float den = 1.0f / (e0 + e1 + e2);
    float a0 = e0 * den, a1 = e1 * den, a2 = e2 * den;
    sw[tid] = a0 * h0 + a1 * h1 + a2 * h2;
    if (tid == 0 && halfsel == 0) {
      size_t aoff = (size_t)B * TT * DD + (size_t)b * 3;
      out[aoff] = a0; out[aoff + 1] = a1; out[aoff + 2] = a2;
    }
  }
  __syncthreads();
  if (tid < DD) {
    float o = bo[tid];
#pragma unroll
    for (int h = 0; h < HH; ++h) o = fmaf(sw[h], Wo[h * DD + tid], o);
    srow[tid] = o;
  }
  __syncthreads();
  const float4 v = *(const float4*)&srow[(tid & 31) * 4];
  const int quarter = TT * DD / 8;   // float4s per half-row
  float4* o4 = (float4*)out + (size_t)b * (TT * DD / 4) + (size_t)halfsel * quarter;
#pragma unroll 4
  for (int i = tid; i < quarter; i += 256) {
    o4[i] = v;   // i mod 32 == tid mod 32 (quarter multiple of 32*... holds)
  }
}

extern "C" void kernel_launch(void* const* d_in, const int* in_sizes, int n_in,
                              void* d_out, int out_size, void* d_ws, size_t ws_size,
                              hipStream_t stream) {
  const float* x    = (const float*)d_in[0];
  const float* ctx  = (const float*)d_in[1];
  const float* W_ih = (const float*)d_in[2];
  const float* W_hh = (const float*)d_in[3];
  const float* b_ih = (const float*)d_in[4];
  const float* b_hh = (const float*)d_in[5];
  const float* Wq   = (const float*)d_in[6];
  const float* bq   = (const float*)d_in[7];
  const float* Ws   = (const float*)d_in[8];
  const float* bs   = (const float*)d_in[9];
  const float* Wo   = (const float*)d_in[10];
  const float* bo   = (const float*)d_in[11];
  const float* logT = (const float*)d_in[12];
  float* out = (float*)d_out;
  const int B = in_sizes[0] / (TT * GG);

  float* hf = (float*)d_ws;  // B*G*H floats

  dim3 g1((B / 16) * GG);
  gru_scan_mfma4<<<g1, 256, 0, stream>>>(x, W_ih, W_hh, b_ih, b_hh, hf, B);
  epilogue<<<2 * B, 256, 0, stream>>>(ctx, hf, Wq, bq, Ws, bs, Wo, bo, logT, out, B);
}

// Round 17
// 245.354 us; speedup vs baseline: 1.0196x; 1.0196x over previous
//
#include <hip/hip_runtime.h>
#include <math.h>

#define TT 512
#define GG 3
#define HH 32
#define DD 128

typedef _Float16 half8 __attribute__((ext_vector_type(8)));
typedef float f32x4 __attribute__((ext_vector_type(4)));

__device__ __forceinline__ uint32_t pack2(float a, float b) {
  auto p = __builtin_amdgcn_cvt_pkrtz(a, b);
  return __builtin_bit_cast(uint32_t, p);
}
__device__ __forceinline__ float fast_tanh(float x) {
  float e = __expf(2.0f * x);
  return 1.0f - 2.0f * __builtin_amdgcn_rcpf(1.0f + e);
}

// Best-known (r15): 16 seqs/block, 4 waves, wave (T,P) owns j-pair; A rows
// permuted so the pair lands in C regs 0,1 (no extraction); biases ride in
// the MFMA C-operand; x double-buffered in registers.
__global__ __launch_bounds__(256) void gru_scan_mfma4(
    const float* __restrict__ x, const float* __restrict__ W_ih,
    const float* __restrict__ W_hh, const float* __restrict__ b_ih,
    const float* __restrict__ b_hh, float* __restrict__ hout, int B) {
  const int tid = threadIdx.x;
  const int wv = tid >> 6;
  const int lane = tid & 63;
  const int col = lane & 15;   // seq for B/C; m-row for A
  const int grp = lane >> 4;   // k-block for A/B; row-group for C
  const int T = wv >> 1;       // j-tile
  const int P = wv & 1;        // j-pair within row-group
  const int nb = B / 16;
  const int g = blockIdx.x / nb;
  const int b0 = (blockIdx.x % nb) * 16;
  const float L2E = 1.44269504088896340736f;

  __shared__ float xlds[16][TT + 1];
  __shared__ uint32_t hbuf[2][16][20];

  // ---- x preload (one-time) ----
#pragma unroll 4
  for (int i = tid; i < 16 * TT; i += 256) {
    int s = i >> 9, t = i & (TT - 1);
    xlds[s][t] = x[((size_t)(b0 + s) * TT + t) * GG + g];
  }

  // ---- A fragments, rows permuted so C regs 0,1 = this wave's j-pair ----
  half8 Af[3];
  const float* Wg = W_hh + (size_t)g * 3 * HH * HH;
  const int wrow = T * 16 + (col & ~3) + 2 * P + (col & 1);
#pragma unroll
  for (int gam = 0; gam < 3; ++gam) {
    const float sc = (gam == 2) ? 2.0f * L2E : -L2E;
    const float* src = Wg + (size_t)(gam * 32 + wrow) * HH + grp * 8;
    half8 a;
#pragma unroll
    for (int i = 0; i < 8; ++i) a[i] = (_Float16)(src[i] * sc);
    Af[gam] = a;
  }

  // ---- bias C-operands + per-wave gate constants (j = T*16+grp*4+2P+k) ----
  f32x4 CinR, CinZ, CinN;
  float wiR[2], wiZ[2], wiN[2], bN[2];
#pragma unroll
  for (int k = 0; k < 2; ++k) {
    int j = T * 16 + grp * 4 + 2 * P + k;
    wiR[k] = W_ih[g * 96 + j] * (-L2E);
    wiZ[k] = W_ih[g * 96 + 32 + j] * (-L2E);
    wiN[k] = W_ih[g * 96 + 64 + j] * (2.0f * L2E);
    bN[k] = b_ih[g * 96 + 64 + j] * (2.0f * L2E);
    float br = (b_ih[g * 96 + j] + b_hh[g * 96 + j]) * (-L2E);
    float bz = (b_ih[g * 96 + 32 + j] + b_hh[g * 96 + 32 + j]) * (-L2E);
    float bn = b_hh[g * 96 + 64 + j] * (2.0f * L2E);
    CinR[k] = br; CinR[k + 2] = br;
    CinZ[k] = bz; CinZ[k + 2] = bz;
    CinN[k] = bn; CinN[k + 2] = bn;
  }

  float ho[2] = {0.0f, 0.0f};
  for (int i = tid; i < 320; i += 256) ((uint32_t*)hbuf)[i] = 0u;  // buf 0
  __syncthreads();

  float xc = xlds[col][0];

#define GRU_STEP(SRC, DST, TNEXT)                                              \
  {                                                                            \
    half8 Bf = *(const half8*)&hbuf[SRC][col][grp * 4];                        \
    float xn = xlds[col][TNEXT];                                               \
    f32x4 Cr = __builtin_amdgcn_mfma_f32_16x16x32_f16(Af[0], Bf, CinR, 0, 0, 0); \
    f32x4 Cz = __builtin_amdgcn_mfma_f32_16x16x32_f16(Af[1], Bf, CinZ, 0, 0, 0); \
    f32x4 Cn = __builtin_amdgcn_mfma_f32_16x16x32_f16(Af[2], Bf, CinN, 0, 0, 0); \
    float pr0 = fmaf(xc, wiR[0], Cr[0]);                                       \
    float pr1 = fmaf(xc, wiR[1], Cr[1]);                                       \
    float rr0 = __builtin_amdgcn_rcpf(1.0f + __builtin_amdgcn_exp2f(pr0));     \
    float rr1 = __builtin_amdgcn_rcpf(1.0f + __builtin_amdgcn_exp2f(pr1));     \
    float pz0 = fmaf(xc, wiZ[0], Cz[0]);                                       \
    float pz1 = fmaf(xc, wiZ[1], Cz[1]);                                       \
    float zz0 = __builtin_amdgcn_rcpf(1.0f + __builtin_amdgcn_exp2f(pz0));     \
    float zz1 = __builtin_amdgcn_rcpf(1.0f + __builtin_amdgcn_exp2f(pz1));     \
    float pn0 = fmaf(rr0, Cn[0], fmaf(xc, wiN[0], bN[0]));                     \
    float pn1 = fmaf(rr1, Cn[1], fmaf(xc, wiN[1], bN[1]));                     \
    float u0 = __builtin_amdgcn_rcpf(1.0f + __builtin_amdgcn_exp2f(pn0));      \
    float u1 = __builtin_amdgcn_rcpf(1.0f + __builtin_amdgcn_exp2f(pn1));      \
    float nn0 = fmaf(-2.0f, u0, 1.0f);                                         \
    float nn1 = fmaf(-2.0f, u1, 1.0f);                                         \
    ho[0] = fmaf(zz0, ho[0] - nn0, nn0);                                       \
    ho[1] = fmaf(zz1, ho[1] - nn1, nn1);                                       \
    hbuf[DST][col][T * 8 + grp * 2 + P] = pack2(ho[0], ho[1]);                 \
    __syncthreads();                                                           \
    xc = xn;                                                                   \
  }

#pragma unroll 1
  for (int t = 0; t < TT; t += 2) {
    GRU_STEP(0, 1, t + 1)
    GRU_STEP(1, 0, (t + 2 < TT) ? (t + 2) : (TT - 1))
  }
#undef GRU_STEP

  {
    int j = T * 16 + grp * 4 + 2 * P;
    size_t base = ((size_t)(b0 + col) * GG + g) * HH + j;
    hout[base] = ho[0];
    hout[base + 1] = ho[1];
  }
}

// One block per b: query -> scores -> softmax -> weighted rep -> out row,
// then broadcast-write the row across all T positions (coalesced float4).
__global__ __launch_bounds__(256) void epilogue(
    const float* __restrict__ ctx, const float* __restrict__ hf,
    const float* __restrict__ Wq, const float* __restrict__ bq,
    const float* __restrict__ Ws, const float* __restrict__ bs,
    const float* __restrict__ Wo, const float* __restrict__ bo,
    const float* __restrict__ logT, float* __restrict__ out, int B) {
  const int b = blockIdx.x;
  const int tid = threadIdx.x;
  __shared__ float sc[DD];
  __shared__ float sw[HH];
  __shared__ float srow[DD];
  if (tid < DD) sc[tid] = ctx[(size_t)b * DD + tid];
  __syncthreads();
  if (tid < HH) {
    float q = bq[tid];
#pragma unroll 4
    for (int d = 0; d < DD; ++d) q = fmaf(sc[d], Wq[d * HH + tid], q);
    float h0 = hf[((size_t)b * 3 + 0) * HH + tid];
    float h1 = hf[((size_t)b * 3 + 1) * HH + tid];
    float h2 = hf[((size_t)b * 3 + 2) * HH + tid];
    float wsv = Ws[tid];
    float s0 = fast_tanh(h0 + q) * wsv;
    float s1 = fast_tanh(h1 + q) * wsv;
    float s2 = fast_tanh(h2 + q) * wsv;
#pragma unroll
    for (int off = 16; off >= 1; off >>= 1) {
      s0 += __shfl_xor(s0, off, 32);
      s1 += __shfl_xor(s1, off, 32);
      s2 += __shfl_xor(s2, off, 32);
    }
    float bsv = bs[0];
    float tmp = fmaxf(__expf(logT[0]), 0.1f);
    float inv = 1.0f / tmp;
    s0 = (s0 + bsv) * inv; s1 = (s1 + bsv) * inv; s2 = (s2 + bsv) * inv;
    float m = fmaxf(s0, fmaxf(s1, s2));
    float e0 = __expf(s0 - m), e1 = __expf(s1 - m), e2 = __expf(s2 - m);
    float den = 1.0f / (e0 + e1 + e2);
    float a0 = e0 * den, a1 = e1 * den, a2 = e2 * den;
    sw[tid] = a0 * h0 + a1 * h1 + a2 * h2;
    if (tid == 0) {
      size_t aoff = (size_t)B * TT * DD + (size_t)b * 3;
      out[aoff] = a0; out[aoff + 1] = a1; out[aoff + 2] = a2;
    }
  }
  __syncthreads();
  if (tid < DD) {
    float o = bo[tid];
#pragma unroll
    for (int h = 0; h < HH; ++h) o = fmaf(sw[h], Wo[h * DD + tid], o);
    srow[tid] = o;
  }
  __syncthreads();
  const float4 v = *(const float4*)&srow[(tid & 31) * 4];
  float4* o4 = (float4*)out + (size_t)b * (TT * DD / 4);
#pragma unroll 4
  for (int i = tid; i < TT * DD / 4; i += 256) {
    o4[i] = v;
  }
}

extern "C" void kernel_launch(void* const* d_in, const int* in_sizes, int n_in,
                              void* d_out, int out_size, void* d_ws, size_t ws_size,
                              hipStream_t stream) {
  const float* x    = (const float*)d_in[0];
  const float* ctx  = (const float*)d_in[1];
  const float* W_ih = (const float*)d_in[2];
  const float* W_hh = (const float*)d_in[3];
  const float* b_ih = (const float*)d_in[4];
  const float* b_hh = (const float*)d_in[5];
  const float* Wq   = (const float*)d_in[6];
  const float* bq   = (const float*)d_in[7];
  const float* Ws   = (const float*)d_in[8];
  const float* bs   = (const float*)d_in[9];
  const float* Wo   = (const float*)d_in[10];
  const float* bo   = (const float*)d_in[11];
  const float* logT = (const float*)d_in[12];
  float* out = (float*)d_out;
  const int B = in_sizes[0] / (TT * GG);

  float* hf = (float*)d_ws;  // B*G*H floats

  dim3 g1((B / 16) * GG);
  gru_scan_mfma4<<<g1, 256, 0, stream>>>(x, W_ih, W_hh, b_ih, b_hh, hf, B);
  epilogue<<<B, 256, 0, stream>>>(ctx, hf, Wq, bq, Ws, bs, Wo, bo, logT, out, B);
}